// Round 10
// baseline (294.620 us; speedup 1.0000x reference)
//
#include <hip/hip_runtime.h>
#include <float.h>

#define NQ    1024
#define JTOT  5120
#define MEML  4096
#define SCL2  0.18033688011112042f   /* 0.125 * log2(e) */

typedef __attribute__((ext_vector_type(8))) short bf16x8;
typedef __attribute__((ext_vector_type(8))) unsigned short ush8;
typedef __attribute__((ext_vector_type(4))) unsigned short ush4;
typedef __attribute__((ext_vector_type(4))) float f32x4;

static __device__ __forceinline__ unsigned short f2bf(float x) {
    union { float f; unsigned u; } v; v.f = x;
    unsigned r = (v.u + 0x7fffu + ((v.u >> 16) & 1u)) >> 16;   // RNE
    return (unsigned short)r;
}
// pack trunc-bf16(f0) (low) | trunc-bf16(f1) (high)
static __device__ __forceinline__ unsigned pack2(float f0, float f1) {
    union { float f; unsigned u; } a, b; a.f = f1; b.f = f0;
    return __builtin_amdgcn_perm(a.u, b.u, 0x07060302u);
}

static __device__ __forceinline__ void gld16(const void* g, void* l) {
    __builtin_amdgcn_global_load_lds(
        (const __attribute__((address_space(1))) unsigned int*)g,
        (__attribute__((address_space(3))) unsigned int*)l, 16, 0, 0);
}

// ---------------------------------------------------------------------------
// prep: one launch. blocks [0,1024): x->bf16; [1024,5120): mem->bf16;
// [5120,5160): mask->bias; [5160,9256): W transpose.
// ---------------------------------------------------------------------------
__global__ __launch_bounds__(256)
void prep_kernel(const float* __restrict__ x, const float* __restrict__ mem,
                 const unsigned char* __restrict__ mask,
                 const float* __restrict__ W0, const float* __restrict__ W1,
                 const float* __restrict__ W2, const float* __restrict__ W3,
                 unsigned short* __restrict__ xb, unsigned short* __restrict__ memb,
                 unsigned short* __restrict__ wt, float* __restrict__ mbp)
{
    __shared__ float Ts[32][33];
    const int bid = blockIdx.x;
    const int t   = threadIdx.x;
    if (bid < 5120) {
        const float* src = (bid < 1024) ? x : mem;
        unsigned short* dst = (bid < 1024) ? xb : memb;
        const size_t i = (size_t)((bid < 1024) ? bid : bid - 1024) * 2048 + t * 8;
        float4 a = *(const float4*)(src + i);
        float4 b = *(const float4*)(src + i + 4);
        ush8 o;
        o[0] = f2bf(a.x); o[1] = f2bf(a.y); o[2] = f2bf(a.z); o[3] = f2bf(a.w);
        o[4] = f2bf(b.x); o[5] = f2bf(b.y); o[6] = f2bf(b.z); o[7] = f2bf(b.w);
        *(ush8*)(dst + i) = o;
    } else if (bid < 5160) {
        const int i = (bid - 5120) * 256 + t;
        mbp[i] = mask[i] ? -1.0e30f : 0.0f;
    } else {
        const int idx = bid - 5160;
        const int z   = idx >> 10;
        const int rem = idx & 1023;
        const float* W = (z == 0) ? W0 : (z == 1) ? W1 : (z == 2) ? W2 : W3;
        unsigned short* D = wt + (size_t)z * 1024 * 1024;
        const int n0 = (rem & 31) * 32, k0 = (rem >> 5) * 32;
        const int tr = t >> 3, tc = (t & 7) * 4;
        float4 v = *(const float4*)(W + (size_t)(k0 + tr) * 1024 + n0 + tc);
        Ts[tr][tc + 0] = v.x; Ts[tr][tc + 1] = v.y;
        Ts[tr][tc + 2] = v.z; Ts[tr][tc + 3] = v.w;
        __syncthreads();
        ush4 o;
        o[0] = f2bf(Ts[tc + 0][tr]); o[1] = f2bf(Ts[tc + 1][tr]);
        o[2] = f2bf(Ts[tc + 2][tr]); o[3] = f2bf(Ts[tc + 3][tr]);
        *(ush4*)(D + (size_t)(n0 + tr) * 1024 + k0 + tc) = o;
    }
}

// ---------------------------------------------------------------------------
// Merged q/k/v GEMM: blocks [0,384) = x @ {Wq,Wk,Wv}; [384,1408) = mem @ {Wk,Wv}.
// R10: 128x128 / BK=64 / 4-wave base (R9: 104 us, best measured) with
//  (a) mode-1 ordering refined for L2-resident windows. R9's bx=i&15 gave a
//      resident set of 16 panels x 4 A-slices = 5 MB > 4 MB L2 -> thrash
//      (FETCH stayed 89 MB). New: two halves of 8 panels; within a half
//      bx = half*8+(j&7), by = 8c+(j>>3) -> resident 64 blocks = 8 panels
//      (2 MB) x 8 A-slices (2 MB) = 4 MB = L2. Bijective.
//  (b) T5 setprio(1) around the MFMA cluster (multi-block-per-CU independent
//      waves — the m191 regime; the 256² had it, the 128² revert dropped it).
// ---------------------------------------------------------------------------
__global__ __launch_bounds__(256)
void mgemm01_kernel(const unsigned short* __restrict__ xb,
                    const unsigned short* __restrict__ memb,
                    const unsigned short* __restrict__ wt,
                    unsigned short* __restrict__ Qb, unsigned short* __restrict__ Kb,
                    unsigned short* __restrict__ Vb,
                    const float* __restrict__ rel_table, const int* __restrict__ rel_idxs)
{
    __shared__ unsigned short Al[128 * 64];
    __shared__ unsigned short Bl[128 * 64];

    const int t    = threadIdx.x;
    const int lane = t & 63;
    const int w    = t >> 6;
    const int wr   = w >> 1, wc = w & 1;
    const int l15  = lane & 15;
    const int quad = lane >> 4;
    const int l7   = l15 & 7;

    const int bid = blockIdx.x;
    int mode, bx, by;
    if (bid < 384) {
        mode = 0;
        const int c = bid & 7, i = bid >> 3;      // 48 logical per XCD
        bx = 3 * c + i % 3;                       // 3 B-panels per XCD
        by = i / 3;                               // 0..15
    } else {
        mode = 1;
        const int p = bid - 384;                  // 384 % 8 == 0 -> c == bid%8
        const int c = p & 7, i = p >> 3;          // 128 logical per XCD
        const int half = i >> 6;                  // two 8-panel halves
        const int j    = i & 63;
        bx = half * 8 + (j & 7);                  // 8 panels per half (2 MB hot)
        by = 8 * c + (j >> 3);                    // 8 A-slices per XCD (2 MB hot)
    }
    const int mat = bx >> 3;
    const int n0  = (bx & 7) * 128;
    const int m0  = by * 128;
    const unsigned short* A = (mode == 0) ? xb : memb;
    const unsigned short* B = wt + (size_t)((mode == 0) ? mat : mat + 1) * 1024 * 1024;

    f32x4 acc[4][4];
    #pragma unroll
    for (int i = 0; i < 4; i++)
        #pragma unroll
        for (int j = 0; j < 4; j++) acc[i][j] = (f32x4){0.f, 0.f, 0.f, 0.f};

    for (int k0 = 0; k0 < 1024; k0 += 64) {
        __syncthreads();
        #pragma unroll
        for (int it = 0; it < 4; it++) {
            const int lin  = it * 256 + t;
            const int row  = lin >> 3;
            const int colb = ((lin & 7) ^ (row & 7)) * 8;   // permuted global chunk
            unsigned short* albase = &Al[(size_t)(it * 256 + w * 64) * 8];
            unsigned short* blbase = &Bl[(size_t)(it * 256 + w * 64) * 8];
            gld16(A + (size_t)(m0 + row) * 1024 + k0 + colb, albase);
            gld16(B + (size_t)(n0 + row) * 1024 + k0 + colb, blbase);
        }
        __syncthreads();
        bf16x8 af[4][2], bfr[4][2];
        #pragma unroll
        for (int i = 0; i < 4; i++) {
            const int R = wr * 64 + i * 16 + l15;
            af[i][0] = *(const bf16x8*)&Al[R * 64 + ((quad ^ l7) << 3)];
            af[i][1] = *(const bf16x8*)&Al[R * 64 + (((4 | quad) ^ l7) << 3)];
        }
        #pragma unroll
        for (int j = 0; j < 4; j++) {
            const int R = wc * 64 + j * 16 + l15;
            bfr[j][0] = *(const bf16x8*)&Bl[R * 64 + ((quad ^ l7) << 3)];
            bfr[j][1] = *(const bf16x8*)&Bl[R * 64 + (((4 | quad) ^ l7) << 3)];
        }
        __builtin_amdgcn_s_setprio(1);
        #pragma unroll
        for (int i = 0; i < 4; i++)
            #pragma unroll
            for (int j = 0; j < 4; j++) {
                acc[i][j] = __builtin_amdgcn_mfma_f32_16x16x32_bf16(af[i][0], bfr[j][0], acc[i][j], 0, 0, 0);
                acc[i][j] = __builtin_amdgcn_mfma_f32_16x16x32_bf16(af[i][1], bfr[j][1], acc[i][j], 0, 0, 0);
            }
        __builtin_amdgcn_s_setprio(0);
    }

    const bool isQ = (mode == 0) && (mat == 0);
    const bool isK = (mode == 0) ? (mat == 1) : (mat == 0);
    if (!isQ && !isK) {                              // V path
        #pragma unroll
        for (int i = 0; i < 4; i++) {
            const int r0 = m0 + wr * 64 + i * 16 + quad * 4;
            const int bb = (mode == 0) ? (r0 >> 10) : (r0 >> 12);
            const int j0 = (mode == 0) ? 4096 + (r0 & 1023) : (r0 & 4095);
            #pragma unroll
            for (int jb = 0; jb < 4; jb++) {
                const int col = n0 + wc * 64 + jb * 16 + l15;
                ush4 o;
                o[0] = f2bf(acc[i][jb][0]); o[1] = f2bf(acc[i][jb][1]);
                o[2] = f2bf(acc[i][jb][2]); o[3] = f2bf(acc[i][jb][3]);
                *(ush4*)(Vb + ((size_t)((bb * 16 + (col >> 6)) * 64 + (col & 63))) * JTOT + j0) = o;
            }
        }
    } else {
        #pragma unroll
        for (int i = 0; i < 4; i++)
            #pragma unroll
            for (int reg = 0; reg < 4; reg++) {
                const int r = m0 + wr * 64 + i * 16 + quad * 4 + reg;
                int bb, idx, chunk;
                if (mode == 0) { bb = r >> 10; idx = isK ? 4096 + (r & 1023) : (r & 1023); chunk = 4; }
                else           { bb = r >> 12; idx = r & 4095; chunk = idx >> 10; }
                #pragma unroll
                for (int jb = 0; jb < 4; jb++) {
                    const int col = n0 + wc * 64 + jb * 16 + l15;
                    const int hh = col >> 6, dh = col & 63;
                    float v = acc[i][jb][reg];
                    if (isK) {
                        v += rel_table[rel_idxs[chunk] * 16 + hh];
                        Kb[((size_t)(bb * 16 + hh) * JTOT + idx) * 64 + dh] = f2bf(v);
                    } else {
                        Qb[((size_t)(bb * 16 + hh) * NQ + idx) * 64 + dh] = f2bf(v);
                    }
                }
            }
    }
}

// ---------------------------------------------------------------------------
// out = ao @ WoT + bo. 64x128 tile, BK=64, swizzled.
// z=1 blocks: copy x -> new_mem (LAST dispatch in graph — survives re-poison).
// ---------------------------------------------------------------------------
__global__ __launch_bounds__(256)
void mgemm2_kernel(const unsigned short* __restrict__ A,
                   const unsigned short* __restrict__ WT,
                   float* __restrict__ outF, const float* __restrict__ bo,
                   const float* __restrict__ x, float* __restrict__ newmem)
{
    __shared__ unsigned short Al[64 * 64];
    __shared__ unsigned short Bl[128 * 64];

    const int t = threadIdx.x;
    if (blockIdx.z == 1) {
        const int blk = blockIdx.y * 8 + blockIdx.x;      // 0..255
        const size_t base = (size_t)blk * 8192 + t * 4;
        #pragma unroll
        for (int i = 0; i < 8; i++)
            *(float4*)(newmem + base + (size_t)i * 1024) =
                *(const float4*)(x + base + (size_t)i * 1024);
        return;
    }

    const int lane = t & 63;
    const int w    = t >> 6;
    const int l15  = lane & 15;
    const int quad = lane >> 4;
    const int l7   = l15 & 7;
    const int n0   = blockIdx.x * 128;
    const int m0   = blockIdx.y * 64;

    f32x4 acc[4][2];
    #pragma unroll
    for (int i = 0; i < 4; i++)
        #pragma unroll
        for (int j = 0; j < 2; j++) acc[i][j] = (f32x4){0.f, 0.f, 0.f, 0.f};

    for (int k0 = 0; k0 < 1024; k0 += 64) {
        __syncthreads();
        #pragma unroll
        for (int it = 0; it < 2; it++) {
            const int lin  = it * 256 + t;
            const int row  = lin >> 3;
            const int colb = ((lin & 7) ^ (row & 7)) * 8;
            gld16(A + (size_t)(m0 + row) * 1024 + k0 + colb,
                  &Al[(size_t)(it * 256 + w * 64) * 8]);
        }
        #pragma unroll
        for (int it = 0; it < 4; it++) {
            const int lin  = it * 256 + t;
            const int row  = lin >> 3;
            const int colb = ((lin & 7) ^ (row & 7)) * 8;
            gld16(WT + (size_t)(n0 + row) * 1024 + k0 + colb,
                  &Bl[(size_t)(it * 256 + w * 64) * 8]);
        }
        __syncthreads();
        bf16x8 af[4][2], bfr[2][2];
        #pragma unroll
        for (int i = 0; i < 4; i++) {
            const int R = i * 16 + l15;
            af[i][0] = *(const bf16x8*)&Al[R * 64 + ((quad ^ l7) << 3)];
            af[i][1] = *(const bf16x8*)&Al[R * 64 + (((4 | quad) ^ l7) << 3)];
        }
        #pragma unroll
        for (int j = 0; j < 2; j++) {
            const int R = w * 32 + j * 16 + l15;
            bfr[j][0] = *(const bf16x8*)&Bl[R * 64 + ((quad ^ l7) << 3)];
            bfr[j][1] = *(const bf16x8*)&Bl[R * 64 + (((4 | quad) ^ l7) << 3)];
        }
        #pragma unroll
        for (int i = 0; i < 4; i++)
            #pragma unroll
            for (int j = 0; j < 2; j++) {
                acc[i][j] = __builtin_amdgcn_mfma_f32_16x16x32_bf16(af[i][0], bfr[j][0], acc[i][j], 0, 0, 0);
                acc[i][j] = __builtin_amdgcn_mfma_f32_16x16x32_bf16(af[i][1], bfr[j][1], acc[i][j], 0, 0, 0);
            }
    }

    #pragma unroll
    for (int i = 0; i < 4; i++)
        #pragma unroll
        for (int reg = 0; reg < 4; reg++) {
            const int r = m0 + i * 16 + quad * 4 + reg;
            #pragma unroll
            for (int j = 0; j < 2; j++) {
                const int col = n0 + w * 32 + j * 16 + l15;
                outF[(size_t)r * 1024 + col] = acc[i][j][reg] + bo[col];
            }
        }
}

// ---------------------------------------------------------------------------
// Flash attention — unchanged from R7 (verified: dropped out of top-5).
// XCD-group swizzle + wave-owns-keys QK + cross-wave Ps/PV + Ls l-reduction.
// ---------------------------------------------------------------------------
__global__ __launch_bounds__(256)
void attn6_kernel(const unsigned short* __restrict__ qh,
                  const unsigned short* __restrict__ kh,
                  const unsigned short* __restrict__ vt,
                  const float* __restrict__ mb,
                  unsigned short* __restrict__ ao)
{
    __shared__ unsigned short Ks[128 * 64];   // [key][dh] swizzled (8-unit rows)
    __shared__ unsigned short Vs[64 * 128];   // [dh][key] swizzled (16-unit rows)
    __shared__ unsigned short Ps[64 * 128];   // [q][key]  swizzled (16-unit rows)
    __shared__ float Ls[4][64];               // per-source-wave l partials

    const int t    = threadIdx.x;
    const int lane = t & 63;
    const int w    = t >> 6;
    const int l15  = lane & 15;
    const int quad = lane >> 4;
    const int l7   = l15 & 7;

    const int flat = blockIdx.x + 16 * blockIdx.y + 256 * blockIdx.z;
    const int xcd  = flat & 7;
    const int idx  = flat >> 3;                  // 0..63
    const int qt   = idx >> 2;                   // 0..15
    const int hb   = (xcd << 2) | (idx & 3);     // 0..31
    const int h    = hb & 15;
    const int b    = hb >> 4;

    const int qbase = qt * 64;
    const int qg    = qbase + w * 16 + l15;

    // ALL 64 q-rows of the block in registers (qb = 0..3)
    bf16x8 bq0[4], bq1[4];
    #pragma unroll
    for (int qb = 0; qb < 4; qb++) {
        const unsigned short* qrow =
            qh + (((size_t)(b * 16 + h) * NQ + qbase + qb * 16 + l15) << 6);
        bq0[qb] = *(const bf16x8*)(qrow + quad * 8);
        bq1[qb] = *(const bf16x8*)(qrow + 32 + quad * 8);
    }

    const int krow = t >> 3;
    const int kcol = (t & 7) * 8;
    const int ksw  = ((t & 7) ^ (krow & 7)) * 8;
    const int vrow = t >> 4;
    const int vu   = t & 15;
    const int vcol = vu * 8;
    const int vsw  = ((vu & 8) | ((vu ^ (vrow & 7)) & 7)) * 8;

    const unsigned short* kbase = kh + (((size_t)(b * 16 + h) * JTOT) << 6);
    const unsigned short* vbase = vt + (((size_t)(b * 16 + h)) << 6) * JTOT;
    const float* mbb = mb + b * JTOT;

    f32x4 oa[4];
    #pragma unroll
    for (int mt = 0; mt < 4; mt++) oa[mt] = (f32x4){0.f, 0.f, 0.f, 0.f};
    float lacc[4] = {0.f, 0.f, 0.f, 0.f};

    const int ntp = (qt + 66) >> 1;           // 128-key tiles (padded)

    ush8 kst[4], vst[4];
    #pragma unroll
    for (int p = 0; p < 4; p++)
        kst[p] = *(const ush8*)(kbase + ((size_t)(krow + 32 * p) << 6) + kcol);
    #pragma unroll
    for (int p = 0; p < 4; p++)
        vst[p] = *(const ush8*)(vbase + (size_t)(vrow + 16 * p) * JTOT + vcol);

    const int prow = (w * 16 + l15) * 128;    // PV read row (this wave's q)

    for (int jt = 0; jt < ntp; jt++) {
        const int jbase = jt * 128;
        __syncthreads();
        #pragma unroll
        for (int p = 0; p < 4; p++)
            *(ush8*)&Ks[(krow + 32 * p) * 64 + ksw] = kst[p];
        #pragma unroll
        for (int p = 0; p < 4; p++)
            *(ush8*)&Vs[(vrow + 16 * p) * 128 + vsw] = vst[p];
        __syncthreads();

        if (jt + 1 < ntp) {
            const int jb2 = jbase + 128;
            #pragma unroll
            for (int p = 0; p < 4; p++)
                kst[p] = *(const ush8*)(kbase + ((size_t)(jb2 + krow + 32 * p) << 6) + kcol);
            #pragma unroll
            for (int p = 0; p < 4; p++)
                vst[p] = *(const ush8*)(vbase + (size_t)(vrow + 16 * p) * JTOT + jb2 + vcol);
        }

        // QK^T: wave w owns keys [32w, 32w+32) x all 64 q
        f32x4 sa[2][4];
        __builtin_amdgcn_s_setprio(1);
        #pragma unroll
        for (int kk = 0; kk < 2; kk++) {
            const int mt2 = 2 * w + kk;
            const int ra  = (mt2 * 16 + l15) * 64;
            const bf16x8 ak0 = *(const bf16x8*)&Ks[ra + ((quad ^ l7) << 3)];
            const bf16x8 ak1 = *(const bf16x8*)&Ks[ra + (((4 | quad) ^ l7) << 3)];
            #pragma unroll
            for (int qb = 0; qb < 4; qb++) {
                f32x4 s = (f32x4){0.f, 0.f, 0.f, 0.f};
                s = __builtin_amdgcn_mfma_f32_16x16x32_bf16(ak0, bq0[qb], s, 0, 0, 0);
                s = __builtin_amdgcn_mfma_f32_16x16x32_bf16(ak1, bq1[qb], s, 0, 0, 0);
                sa[kk][qb] = s;
            }
        }
        __builtin_amdgcn_s_setprio(0);

        // scale (exp2 domain) + key-mask bias (key depends on kk only)
        #pragma unroll
        for (int kk = 0; kk < 2; kk++) {
            const float4 mv = *(const float4*)(mbb + jbase + (2 * w + kk) * 16 + quad * 4);
            #pragma unroll
            for (int qb = 0; qb < 4; qb++) {
                sa[kk][qb][0] = sa[kk][qb][0] * SCL2 + mv.x;
                sa[kk][qb][1] = sa[kk][qb][1] * SCL2 + mv.y;
                sa[kk][qb][2] = sa[kk][qb][2] * SCL2 + mv.z;
                sa[kk][qb][3] = sa[kk][qb][3] * SCL2 + mv.w;
            }
        }
        // causal (+pad) mask: only the last tile contains the boundary
        if (jt == ntp - 1) {
            #pragma unroll
            for (int qb = 0; qb < 4; qb++) {
                const int tl = qbase + qb * 16 + l15 + 4096 - jbase;
                #pragma unroll
                for (int kk = 0; kk < 2; kk++)
                    #pragma unroll
                    for (int r = 0; r < 4; r++)
                        if ((2 * w + kk) * 16 + quad * 4 + r > tl) sa[kk][qb][r] = -1.0e30f;
            }
        }

        // softmax numerator (per-lane); l partial per (lane, qb)
        #pragma unroll
        for (int kk = 0; kk < 2; kk++)
            #pragma unroll
            for (int qb = 0; qb < 4; qb++)
                #pragma unroll
                for (int r = 0; r < 4; r++) {
                    const float pv = __builtin_amdgcn_exp2f(sa[kk][qb][r]);
                    sa[kk][qb][r] = pv;
                    lacc[qb] += pv;
                }

        // P -> Ps[q][key]: rows qb*16+l15, key-group u = 4w + 2kk + (quad>>1)
        #pragma unroll
        for (int kk = 0; kk < 2; kk++) {
            const int u  = 4 * w + 2 * kk + (quad >> 1);
            const int up = (u & 8) | ((u ^ l7) & 7);
            #pragma unroll
            for (int qb = 0; qb < 4; qb++) {
                uint2 pk;
                pk.x = pack2(sa[kk][qb][0], sa[kk][qb][1]);
                pk.y = pack2(sa[kk][qb][2], sa[kk][qb][3]);
                *(uint2*)&Ps[(qb * 16 + l15) * 128 + up * 8 + (quad & 1) * 4] = pk;
            }
        }
        __syncthreads();          // Ps is cross-wave now

        // O^T += V^T.P^T (each wave: its 16 q, full key range)
        __builtin_amdgcn_s_setprio(1);
        #pragma unroll
        for (int s = 0; s < 4; s++) {
            const int u  = quad + 4 * s;
            const int up = (u & 8) | ((u ^ l7) & 7);
            const bf16x8 bp = *(const bf16x8*)&Ps[prow + up * 8];
            #pragma unroll
            for (int mt = 0; mt < 4; mt++) {
                const bf16x8 av = *(const bf16x8*)&Vs[(mt * 16 + l15) * 128 + up * 8];
                oa[mt] = __builtin_amdgcn_mfma_f32_16x16x32_bf16(av, bp, oa[mt], 0, 0, 0);
            }
        }
        __builtin_amdgcn_s_setprio(0);
    }

    // epilogue: l = sum over quads (shfl) and waves (Ls) of lacc partials.
    #pragma unroll
    for (int qb = 0; qb < 4; qb++) {
        lacc[qb] += __shfl_xor(lacc[qb], 16);
        lacc[qb] += __shfl_xor(lacc[qb], 32);
    }
    if (quad == 0) {
        #pragma unroll
        for (int qb = 0; qb < 4; qb++) Ls[w][qb * 16 + l15] = lacc[qb];
    }
    __syncthreads();
    const float l = Ls[0][w * 16 + l15] + Ls[1][w * 16 + l15] +
                    Ls[2][w * 16 + l15] + Ls[3][w * 16 + l15];
    const float inv = 1.0f / l;
    unsigned short* arow = ao + ((size_t)(b * NQ + qg)) * 1024 + h * 64;
    #pragma unroll
    for (int mt = 0; mt < 4; mt++) {
        ush4 o;
        o[0] = f2bf(oa[mt][0] * inv); o[1] = f2bf(oa[mt][1] * inv);
        o[2] = f2bf(oa[mt][2] * inv); o[3] = f2bf(oa[mt][3] * inv);
        *(ush4*)(arow + mt * 16 + quad * 4) = o;
    }
}

// ---------------------------------------------------------------------------
extern "C" void kernel_launch(void* const* d_in, const int* in_sizes, int n_in,
                              void* d_out, int out_size, void* d_ws, size_t ws_size,
                              hipStream_t stream)
{
    const float* x        = (const float*)d_in[0];
    const float* mem      = (const float*)d_in[1];
    const unsigned char* mask = (const unsigned char*)d_in[2];
    const int*   rel_idxs = (const int*)d_in[3];
    const float* Wq       = (const float*)d_in[4];
    const float* Wk       = (const float*)d_in[5];
    const float* Wv       = (const float*)d_in[6];
    const float* Wo       = (const float*)d_in[7];
    const float* bo       = (const float*)d_in[8];
    const float* rel_table= (const float*)d_in[9];

    float* out = (float*)d_out;
    const size_t M1 = (size_t)1024 * 1024;
    unsigned short* xb   = (unsigned short*)d_ws;   //  2M
    unsigned short* memb = xb   + 2 * M1;           //  8M
    unsigned short* wt   = memb + 8 * M1;           //  4M
    unsigned short* qb   = wt   + 4 * M1;           //  2M  qh[b][h][q][dh]
    unsigned short* kb   = qb   + 2 * M1;           // 10M  kh[b][h][j][dh]
    unsigned short* vb   = kb   + 10 * M1;          // 10M  vt[b][h][dh][j]
    unsigned short* aob  = vb   + 10 * M1;          //  2M
    float* mbp = (float*)(aob + 2 * M1);            // 10240 floats

    prep_kernel<<<9256, 256, 0, stream>>>(
        x, mem, mask, Wq, Wk, Wv, Wo, xb, memb, wt, mbp);
    mgemm01_kernel<<<1408, 256, 0, stream>>>(
        xb, memb, wt, qb, kb, vb, rel_table, rel_idxs);
    attn6_kernel<<<dim3(16, 16, 2), 256, 0, stream>>>(qb, kb, vb, mbp, aob);
    // last dispatch: out-projection (z=0) + new_mem copy (z=1)
    mgemm2_kernel<<<dim3(8, 32, 2), 256, 0, stream>>>(
        aob, wt + 3 * M1, out, bo, x, out + (size_t)2048 * 1024);
}

// Round 11
// 278.677 us; speedup vs baseline: 1.0572x; 1.0572x over previous
//
#include <hip/hip_runtime.h>
#include <float.h>

#define NQ    1024
#define JTOT  5120
#define MEML  4096
#define SCL2  0.18033688011112042f   /* 0.125 * log2(e) */

typedef __attribute__((ext_vector_type(8))) short bf16x8;
typedef __attribute__((ext_vector_type(8))) unsigned short ush8;
typedef __attribute__((ext_vector_type(4))) unsigned short ush4;
typedef __attribute__((ext_vector_type(4))) float f32x4;

static __device__ __forceinline__ unsigned short f2bf(float x) {
    union { float f; unsigned u; } v; v.f = x;
    unsigned r = (v.u + 0x7fffu + ((v.u >> 16) & 1u)) >> 16;   // RNE
    return (unsigned short)r;
}
// pack trunc-bf16(f0) (low) | trunc-bf16(f1) (high)
static __device__ __forceinline__ unsigned pack2(float f0, float f1) {
    union { float f; unsigned u; } a, b; a.f = f1; b.f = f0;
    return __builtin_amdgcn_perm(a.u, b.u, 0x07060302u);
}

static __device__ __forceinline__ void gld16(const void* g, void* l) {
    __builtin_amdgcn_global_load_lds(
        (const __attribute__((address_space(1))) unsigned int*)g,
        (__attribute__((address_space(3))) unsigned int*)l, 16, 0, 0);
}

// ---------------------------------------------------------------------------
// prep: one launch. blocks [0,1024): x->bf16; [1024,5120): mem->bf16;
// [5120,5160): mask->bias; [5160,9256): W transpose.
// ---------------------------------------------------------------------------
__global__ __launch_bounds__(256)
void prep_kernel(const float* __restrict__ x, const float* __restrict__ mem,
                 const unsigned char* __restrict__ mask,
                 const float* __restrict__ W0, const float* __restrict__ W1,
                 const float* __restrict__ W2, const float* __restrict__ W3,
                 unsigned short* __restrict__ xb, unsigned short* __restrict__ memb,
                 unsigned short* __restrict__ wt, float* __restrict__ mbp)
{
    __shared__ float Ts[32][33];
    const int bid = blockIdx.x;
    const int t   = threadIdx.x;
    if (bid < 5120) {
        const float* src = (bid < 1024) ? x : mem;
        unsigned short* dst = (bid < 1024) ? xb : memb;
        const size_t i = (size_t)((bid < 1024) ? bid : bid - 1024) * 2048 + t * 8;
        float4 a = *(const float4*)(src + i);
        float4 b = *(const float4*)(src + i + 4);
        ush8 o;
        o[0] = f2bf(a.x); o[1] = f2bf(a.y); o[2] = f2bf(a.z); o[3] = f2bf(a.w);
        o[4] = f2bf(b.x); o[5] = f2bf(b.y); o[6] = f2bf(b.z); o[7] = f2bf(b.w);
        *(ush8*)(dst + i) = o;
    } else if (bid < 5160) {
        const int i = (bid - 5120) * 256 + t;
        mbp[i] = mask[i] ? -1.0e30f : 0.0f;
    } else {
        const int idx = bid - 5160;
        const int z   = idx >> 10;
        const int rem = idx & 1023;
        const float* W = (z == 0) ? W0 : (z == 1) ? W1 : (z == 2) ? W2 : W3;
        unsigned short* D = wt + (size_t)z * 1024 * 1024;
        const int n0 = (rem & 31) * 32, k0 = (rem >> 5) * 32;
        const int tr = t >> 3, tc = (t & 7) * 4;
        float4 v = *(const float4*)(W + (size_t)(k0 + tr) * 1024 + n0 + tc);
        Ts[tr][tc + 0] = v.x; Ts[tr][tc + 1] = v.y;
        Ts[tr][tc + 2] = v.z; Ts[tr][tc + 3] = v.w;
        __syncthreads();
        ush4 o;
        o[0] = f2bf(Ts[tc + 0][tr]); o[1] = f2bf(Ts[tc + 1][tr]);
        o[2] = f2bf(Ts[tc + 2][tr]); o[3] = f2bf(Ts[tc + 3][tr]);
        *(ush4*)(D + (size_t)(n0 + tr) * 1024 + k0 + tc) = o;
    }
}

// ---------------------------------------------------------------------------
// Merged q/k/v GEMM: blocks [0,384) = x @ {Wq,Wk,Wv}; [384,1408) = mem @ {Wk,Wv}.
// R11: minimum 2-phase prefetch (T3 recipe) on the 128x128/BK=64/4-wave base.
// R10 resolved the pre-registered fork: FETCH 89->67 MB but time flat =>
// miss-LATENCY-bound. Old per-K-step order (barrier -> STAGE same buf ->
// barrier[vmcnt(0) drain] -> compute) eats the full L3 round-trip serially.
// New: double-buffer as FOUR DISTINCT __shared__ objects (Al0/Bl0/Al1/Bl1,
// 64 KB -> still 2 blocks/CU), K-loop unrolled by 2 (textual buffer choice);
// per step: STAGE(next buf) -> ds_read+MFMA(cur buf) -> __syncthreads().
// The end-of-body barrier drains vmcnt(0) AFTER ~350cy of compute has run
// since issue -> residual stall = max(0, lat - compute) instead of full lat.
// WAR safe: reads of buf X drain (lgkmcnt(0) at barrier) one half-iteration
// before X is re-staged. Distinct objects keep the compiler from pinning a
// vmcnt wait before the current-buffer ds_reads (LDS-DMA alias hazard).
// setprio dropped (R10: mildly negative; m190 lockstep-GEMM null).
// Grid map keeps R10's 8x8 L2-resident windows (FETCH 67 MB, verified).
// ---------------------------------------------------------------------------
__global__ __launch_bounds__(256)
void mgemm01_kernel(const unsigned short* __restrict__ xb,
                    const unsigned short* __restrict__ memb,
                    const unsigned short* __restrict__ wt,
                    unsigned short* __restrict__ Qb, unsigned short* __restrict__ Kb,
                    unsigned short* __restrict__ Vb,
                    const float* __restrict__ rel_table, const int* __restrict__ rel_idxs)
{
    __shared__ unsigned short Al0[128 * 64], Bl0[128 * 64];
    __shared__ unsigned short Al1[128 * 64], Bl1[128 * 64];

    const int t    = threadIdx.x;
    const int lane = t & 63;
    const int w    = t >> 6;
    const int wr   = w >> 1, wc = w & 1;
    const int l15  = lane & 15;
    const int quad = lane >> 4;
    const int l7   = l15 & 7;

    const int bid = blockIdx.x;
    int mode, bx, by;
    if (bid < 384) {
        mode = 0;
        const int c = bid & 7, i = bid >> 3;      // 48 logical per XCD
        bx = 3 * c + i % 3;                       // 3 B-panels per XCD
        by = i / 3;                               // 0..15
    } else {
        mode = 1;
        const int p = bid - 384;                  // 384 % 8 == 0 -> c == bid%8
        const int c = p & 7, i = p >> 3;          // 128 logical per XCD
        const int half = i >> 6;                  // two 8-panel halves
        const int j    = i & 63;
        bx = half * 8 + (j & 7);                  // 8 panels per half (2 MB hot)
        by = 8 * c + (j >> 3);                    // 8 A-slices per XCD (2 MB hot)
    }
    const int mat = bx >> 3;
    const int n0  = (bx & 7) * 128;
    const int m0  = by * 128;
    const unsigned short* A = (mode == 0) ? xb : memb;
    const unsigned short* B = wt + (size_t)((mode == 0) ? mat : mat + 1) * 1024 * 1024;

    // 8 gld16/wave: stage one 128x64 A-tile + B-tile into given buffers
    auto stage = [&](unsigned short* Ad, unsigned short* Bd, int k0) {
        #pragma unroll
        for (int it = 0; it < 4; it++) {
            const int lin  = it * 256 + t;
            const int row  = lin >> 3;
            const int colb = ((lin & 7) ^ (row & 7)) * 8;   // permuted global chunk
            gld16(A + (size_t)(m0 + row) * 1024 + k0 + colb,
                  Ad + (size_t)(it * 256 + w * 64) * 8);
            gld16(B + (size_t)(n0 + row) * 1024 + k0 + colb,
                  Bd + (size_t)(it * 256 + w * 64) * 8);
        }
    };

    f32x4 acc[4][4];
    #pragma unroll
    for (int i = 0; i < 4; i++)
        #pragma unroll
        for (int j = 0; j < 4; j++) acc[i][j] = (f32x4){0.f, 0.f, 0.f, 0.f};

    auto compute = [&](const unsigned short* As, const unsigned short* Bs) {
        bf16x8 af[4][2], bfr[4][2];
        #pragma unroll
        for (int i = 0; i < 4; i++) {
            const int R = wr * 64 + i * 16 + l15;
            af[i][0] = *(const bf16x8*)&As[R * 64 + ((quad ^ l7) << 3)];
            af[i][1] = *(const bf16x8*)&As[R * 64 + (((4 | quad) ^ l7) << 3)];
        }
        #pragma unroll
        for (int j = 0; j < 4; j++) {
            const int R = wc * 64 + j * 16 + l15;
            bfr[j][0] = *(const bf16x8*)&Bs[R * 64 + ((quad ^ l7) << 3)];
            bfr[j][1] = *(const bf16x8*)&Bs[R * 64 + (((4 | quad) ^ l7) << 3)];
        }
        #pragma unroll
        for (int i = 0; i < 4; i++)
            #pragma unroll
            for (int j = 0; j < 4; j++) {
                acc[i][j] = __builtin_amdgcn_mfma_f32_16x16x32_bf16(af[i][0], bfr[j][0], acc[i][j], 0, 0, 0);
                acc[i][j] = __builtin_amdgcn_mfma_f32_16x16x32_bf16(af[i][1], bfr[j][1], acc[i][j], 0, 0, 0);
            }
    };

    // prologue: tile 0 into buf0; drain; barrier.
    stage(Al0, Bl0, 0);
    __syncthreads();
    // main loop: 16 K-tiles, unrolled x2 for textual buffer selection.
    // Body: STAGE(next) -> compute(cur) -> barrier(drains vmcnt+lgkm).
    for (int e = 0; e < 14; e += 2) {
        stage(Al1, Bl1, (e + 1) << 6);
        compute(Al0, Bl0);
        __syncthreads();
        stage(Al0, Bl0, (e + 2) << 6);
        compute(Al1, Bl1);
        __syncthreads();
    }
    stage(Al1, Bl1, 15 << 6);
    compute(Al0, Bl0);
    __syncthreads();
    compute(Al1, Bl1);

    const bool isQ = (mode == 0) && (mat == 0);
    const bool isK = (mode == 0) ? (mat == 1) : (mat == 0);
    if (!isQ && !isK) {                              // V path
        #pragma unroll
        for (int i = 0; i < 4; i++) {
            const int r0 = m0 + wr * 64 + i * 16 + quad * 4;
            const int bb = (mode == 0) ? (r0 >> 10) : (r0 >> 12);
            const int j0 = (mode == 0) ? 4096 + (r0 & 1023) : (r0 & 4095);
            #pragma unroll
            for (int jb = 0; jb < 4; jb++) {
                const int col = n0 + wc * 64 + jb * 16 + l15;
                ush4 o;
                o[0] = f2bf(acc[i][jb][0]); o[1] = f2bf(acc[i][jb][1]);
                o[2] = f2bf(acc[i][jb][2]); o[3] = f2bf(acc[i][jb][3]);
                *(ush4*)(Vb + ((size_t)((bb * 16 + (col >> 6)) * 64 + (col & 63))) * JTOT + j0) = o;
            }
        }
    } else {
        #pragma unroll
        for (int i = 0; i < 4; i++)
            #pragma unroll
            for (int reg = 0; reg < 4; reg++) {
                const int r = m0 + wr * 64 + i * 16 + quad * 4 + reg;
                int bb, idx, chunk;
                if (mode == 0) { bb = r >> 10; idx = isK ? 4096 + (r & 1023) : (r & 1023); chunk = 4; }
                else           { bb = r >> 12; idx = r & 4095; chunk = idx >> 10; }
                #pragma unroll
                for (int jb = 0; jb < 4; jb++) {
                    const int col = n0 + wc * 64 + jb * 16 + l15;
                    const int hh = col >> 6, dh = col & 63;
                    float v = acc[i][jb][reg];
                    if (isK) {
                        v += rel_table[rel_idxs[chunk] * 16 + hh];
                        Kb[((size_t)(bb * 16 + hh) * JTOT + idx) * 64 + dh] = f2bf(v);
                    } else {
                        Qb[((size_t)(bb * 16 + hh) * NQ + idx) * 64 + dh] = f2bf(v);
                    }
                }
            }
    }
}

// ---------------------------------------------------------------------------
// out = ao @ WoT + bo. 64x128 tile, BK=64, swizzled.
// z=1 blocks: copy x -> new_mem (LAST dispatch in graph — survives re-poison).
// ---------------------------------------------------------------------------
__global__ __launch_bounds__(256)
void mgemm2_kernel(const unsigned short* __restrict__ A,
                   const unsigned short* __restrict__ WT,
                   float* __restrict__ outF, const float* __restrict__ bo,
                   const float* __restrict__ x, float* __restrict__ newmem)
{
    __shared__ unsigned short Al[64 * 64];
    __shared__ unsigned short Bl[128 * 64];

    const int t = threadIdx.x;
    if (blockIdx.z == 1) {
        const int blk = blockIdx.y * 8 + blockIdx.x;      // 0..255
        const size_t base = (size_t)blk * 8192 + t * 4;
        #pragma unroll
        for (int i = 0; i < 8; i++)
            *(float4*)(newmem + base + (size_t)i * 1024) =
                *(const float4*)(x + base + (size_t)i * 1024);
        return;
    }

    const int lane = t & 63;
    const int w    = t >> 6;
    const int l15  = lane & 15;
    const int quad = lane >> 4;
    const int l7   = l15 & 7;
    const int n0   = blockIdx.x * 128;
    const int m0   = blockIdx.y * 64;

    f32x4 acc[4][2];
    #pragma unroll
    for (int i = 0; i < 4; i++)
        #pragma unroll
        for (int j = 0; j < 2; j++) acc[i][j] = (f32x4){0.f, 0.f, 0.f, 0.f};

    for (int k0 = 0; k0 < 1024; k0 += 64) {
        __syncthreads();
        #pragma unroll
        for (int it = 0; it < 2; it++) {
            const int lin  = it * 256 + t;
            const int row  = lin >> 3;
            const int colb = ((lin & 7) ^ (row & 7)) * 8;
            gld16(A + (size_t)(m0 + row) * 1024 + k0 + colb,
                  &Al[(size_t)(it * 256 + w * 64) * 8]);
        }
        #pragma unroll
        for (int it = 0; it < 4; it++) {
            const int lin  = it * 256 + t;
            const int row  = lin >> 3;
            const int colb = ((lin & 7) ^ (row & 7)) * 8;
            gld16(WT + (size_t)(n0 + row) * 1024 + k0 + colb,
                  &Bl[(size_t)(it * 256 + w * 64) * 8]);
        }
        __syncthreads();
        bf16x8 af[4][2], bfr[2][2];
        #pragma unroll
        for (int i = 0; i < 4; i++) {
            const int R = i * 16 + l15;
            af[i][0] = *(const bf16x8*)&Al[R * 64 + ((quad ^ l7) << 3)];
            af[i][1] = *(const bf16x8*)&Al[R * 64 + (((4 | quad) ^ l7) << 3)];
        }
        #pragma unroll
        for (int j = 0; j < 2; j++) {
            const int R = w * 32 + j * 16 + l15;
            bfr[j][0] = *(const bf16x8*)&Bl[R * 64 + ((quad ^ l7) << 3)];
            bfr[j][1] = *(const bf16x8*)&Bl[R * 64 + (((4 | quad) ^ l7) << 3)];
        }
        #pragma unroll
        for (int i = 0; i < 4; i++)
            #pragma unroll
            for (int j = 0; j < 2; j++) {
                acc[i][j] = __builtin_amdgcn_mfma_f32_16x16x32_bf16(af[i][0], bfr[j][0], acc[i][j], 0, 0, 0);
                acc[i][j] = __builtin_amdgcn_mfma_f32_16x16x32_bf16(af[i][1], bfr[j][1], acc[i][j], 0, 0, 0);
            }
    }

    #pragma unroll
    for (int i = 0; i < 4; i++)
        #pragma unroll
        for (int reg = 0; reg < 4; reg++) {
            const int r = m0 + i * 16 + quad * 4 + reg;
            #pragma unroll
            for (int j = 0; j < 2; j++) {
                const int col = n0 + w * 32 + j * 16 + l15;
                outF[(size_t)r * 1024 + col] = acc[i][j][reg] + bo[col];
            }
        }
}

// ---------------------------------------------------------------------------
// Flash attention — unchanged from R7 (verified: dropped out of top-5).
// XCD-group swizzle + wave-owns-keys QK + cross-wave Ps/PV + Ls l-reduction.
// ---------------------------------------------------------------------------
__global__ __launch_bounds__(256)
void attn6_kernel(const unsigned short* __restrict__ qh,
                  const unsigned short* __restrict__ kh,
                  const unsigned short* __restrict__ vt,
                  const float* __restrict__ mb,
                  unsigned short* __restrict__ ao)
{
    __shared__ unsigned short Ks[128 * 64];   // [key][dh] swizzled (8-unit rows)
    __shared__ unsigned short Vs[64 * 128];   // [dh][key] swizzled (16-unit rows)
    __shared__ unsigned short Ps[64 * 128];   // [q][key]  swizzled (16-unit rows)
    __shared__ float Ls[4][64];               // per-source-wave l partials

    const int t    = threadIdx.x;
    const int lane = t & 63;
    const int w    = t >> 6;
    const int l15  = lane & 15;
    const int quad = lane >> 4;
    const int l7   = l15 & 7;

    const int flat = blockIdx.x + 16 * blockIdx.y + 256 * blockIdx.z;
    const int xcd  = flat & 7;
    const int idx  = flat >> 3;                  // 0..63
    const int qt   = idx >> 2;                   // 0..15
    const int hb   = (xcd << 2) | (idx & 3);     // 0..31
    const int h    = hb & 15;
    const int b    = hb >> 4;

    const int qbase = qt * 64;
    const int qg    = qbase + w * 16 + l15;

    // ALL 64 q-rows of the block in registers (qb = 0..3)
    bf16x8 bq0[4], bq1[4];
    #pragma unroll
    for (int qb = 0; qb < 4; qb++) {
        const unsigned short* qrow =
            qh + (((size_t)(b * 16 + h) * NQ + qbase + qb * 16 + l15) << 6);
        bq0[qb] = *(const bf16x8*)(qrow + quad * 8);
        bq1[qb] = *(const bf16x8*)(qrow + 32 + quad * 8);
    }

    const int krow = t >> 3;
    const int kcol = (t & 7) * 8;
    const int ksw  = ((t & 7) ^ (krow & 7)) * 8;
    const int vrow = t >> 4;
    const int vu   = t & 15;
    const int vcol = vu * 8;
    const int vsw  = ((vu & 8) | ((vu ^ (vrow & 7)) & 7)) * 8;

    const unsigned short* kbase = kh + (((size_t)(b * 16 + h) * JTOT) << 6);
    const unsigned short* vbase = vt + (((size_t)(b * 16 + h)) << 6) * JTOT;
    const float* mbb = mb + b * JTOT;

    f32x4 oa[4];
    #pragma unroll
    for (int mt = 0; mt < 4; mt++) oa[mt] = (f32x4){0.f, 0.f, 0.f, 0.f};
    float lacc[4] = {0.f, 0.f, 0.f, 0.f};

    const int ntp = (qt + 66) >> 1;           // 128-key tiles (padded)

    ush8 kst[4], vst[4];
    #pragma unroll
    for (int p = 0; p < 4; p++)
        kst[p] = *(const ush8*)(kbase + ((size_t)(krow + 32 * p) << 6) + kcol);
    #pragma unroll
    for (int p = 0; p < 4; p++)
        vst[p] = *(const ush8*)(vbase + (size_t)(vrow + 16 * p) * JTOT + vcol);

    const int prow = (w * 16 + l15) * 128;    // PV read row (this wave's q)

    for (int jt = 0; jt < ntp; jt++) {
        const int jbase = jt * 128;
        __syncthreads();
        #pragma unroll
        for (int p = 0; p < 4; p++)
            *(ush8*)&Ks[(krow + 32 * p) * 64 + ksw] = kst[p];
        #pragma unroll
        for (int p = 0; p < 4; p++)
            *(ush8*)&Vs[(vrow + 16 * p) * 128 + vsw] = vst[p];
        __syncthreads();

        if (jt + 1 < ntp) {
            const int jb2 = jbase + 128;
            #pragma unroll
            for (int p = 0; p < 4; p++)
                kst[p] = *(const ush8*)(kbase + ((size_t)(jb2 + krow + 32 * p) << 6) + kcol);
            #pragma unroll
            for (int p = 0; p < 4; p++)
                vst[p] = *(const ush8*)(vbase + (size_t)(vrow + 16 * p) * JTOT + jb2 + vcol);
        }

        // QK^T: wave w owns keys [32w, 32w+32) x all 64 q
        f32x4 sa[2][4];
        __builtin_amdgcn_s_setprio(1);
        #pragma unroll
        for (int kk = 0; kk < 2; kk++) {
            const int mt2 = 2 * w + kk;
            const int ra  = (mt2 * 16 + l15) * 64;
            const bf16x8 ak0 = *(const bf16x8*)&Ks[ra + ((quad ^ l7) << 3)];
            const bf16x8 ak1 = *(const bf16x8*)&Ks[ra + (((4 | quad) ^ l7) << 3)];
            #pragma unroll
            for (int qb = 0; qb < 4; qb++) {
                f32x4 s = (f32x4){0.f, 0.f, 0.f, 0.f};
                s = __builtin_amdgcn_mfma_f32_16x16x32_bf16(ak0, bq0[qb], s, 0, 0, 0);
                s = __builtin_amdgcn_mfma_f32_16x16x32_bf16(ak1, bq1[qb], s, 0, 0, 0);
                sa[kk][qb] = s;
            }
        }
        __builtin_amdgcn_s_setprio(0);

        // scale (exp2 domain) + key-mask bias (key depends on kk only)
        #pragma unroll
        for (int kk = 0; kk < 2; kk++) {
            const float4 mv = *(const float4*)(mbb + jbase + (2 * w + kk) * 16 + quad * 4);
            #pragma unroll
            for (int qb = 0; qb < 4; qb++) {
                sa[kk][qb][0] = sa[kk][qb][0] * SCL2 + mv.x;
                sa[kk][qb][1] = sa[kk][qb][1] * SCL2 + mv.y;
                sa[kk][qb][2] = sa[kk][qb][2] * SCL2 + mv.z;
                sa[kk][qb][3] = sa[kk][qb][3] * SCL2 + mv.w;
            }
        }
        // causal (+pad) mask: only the last tile contains the boundary
        if (jt == ntp - 1) {
            #pragma unroll
            for (int qb = 0; qb < 4; qb++) {
                const int tl = qbase + qb * 16 + l15 + 4096 - jbase;
                #pragma unroll
                for (int kk = 0; kk < 2; kk++)
                    #pragma unroll
                    for (int r = 0; r < 4; r++)
                        if ((2 * w + kk) * 16 + quad * 4 + r > tl) sa[kk][qb][r] = -1.0e30f;
            }
        }

        // softmax numerator (per-lane); l partial per (lane, qb)
        #pragma unroll
        for (int kk = 0; kk < 2; kk++)
            #pragma unroll
            for (int qb = 0; qb < 4; qb++)
                #pragma unroll
                for (int r = 0; r < 4; r++) {
                    const float pv = __builtin_amdgcn_exp2f(sa[kk][qb][r]);
                    sa[kk][qb][r] = pv;
                    lacc[qb] += pv;
                }

        // P -> Ps[q][key]: rows qb*16+l15, key-group u = 4w + 2kk + (quad>>1)
        #pragma unroll
        for (int kk = 0; kk < 2; kk++) {
            const int u  = 4 * w + 2 * kk + (quad >> 1);
            const int up = (u & 8) | ((u ^ l7) & 7);
            #pragma unroll
            for (int qb = 0; qb < 4; qb++) {
                uint2 pk;
                pk.x = pack2(sa[kk][qb][0], sa[kk][qb][1]);
                pk.y = pack2(sa[kk][qb][2], sa[kk][qb][3]);
                *(uint2*)&Ps[(qb * 16 + l15) * 128 + up * 8 + (quad & 1) * 4] = pk;
            }
        }
        __syncthreads();          // Ps is cross-wave now

        // O^T += V^T.P^T (each wave: its 16 q, full key range)
        __builtin_amdgcn_s_setprio(1);
        #pragma unroll
        for (int s = 0; s < 4; s++) {
            const int u  = quad + 4 * s;
            const int up = (u & 8) | ((u ^ l7) & 7);
            const bf16x8 bp = *(const bf16x8*)&Ps[prow + up * 8];
            #pragma unroll
            for (int mt = 0; mt < 4; mt++) {
                const bf16x8 av = *(const bf16x8*)&Vs[(mt * 16 + l15) * 128 + up * 8];
                oa[mt] = __builtin_amdgcn_mfma_f32_16x16x32_bf16(av, bp, oa[mt], 0, 0, 0);
            }
        }
        __builtin_amdgcn_s_setprio(0);
    }

    // epilogue: l = sum over quads (shfl) and waves (Ls) of lacc partials.
    #pragma unroll
    for (int qb = 0; qb < 4; qb++) {
        lacc[qb] += __shfl_xor(lacc[qb], 16);
        lacc[qb] += __shfl_xor(lacc[qb], 32);
    }
    if (quad == 0) {
        #pragma unroll
        for (int qb = 0; qb < 4; qb++) Ls[w][qb * 16 + l15] = lacc[qb];
    }
    __syncthreads();
    const float l = Ls[0][w * 16 + l15] + Ls[1][w * 16 + l15] +
                    Ls[2][w * 16 + l15] + Ls[3][w * 16 + l15];
    const float inv = 1.0f / l;
    unsigned short* arow = ao + ((size_t)(b * NQ + qg)) * 1024 + h * 64;
    #pragma unroll
    for (int mt = 0; mt < 4; mt++) {
        ush4 o;
        o[0] = f2bf(oa[mt][0] * inv); o[1] = f2bf(oa[mt][1] * inv);
        o[2] = f2bf(oa[mt][2] * inv); o[3] = f2bf(oa[mt][3] * inv);
        *(ush4*)(arow + mt * 16 + quad * 4) = o;
    }
}

// ---------------------------------------------------------------------------
extern "C" void kernel_launch(void* const* d_in, const int* in_sizes, int n_in,
                              void* d_out, int out_size, void* d_ws, size_t ws_size,
                              hipStream_t stream)
{
    const float* x        = (const float*)d_in[0];
    const float* mem      = (const float*)d_in[1];
    const unsigned char* mask = (const unsigned char*)d_in[2];
    const int*   rel_idxs = (const int*)d_in[3];
    const float* Wq       = (const float*)d_in[4];
    const float* Wk       = (const float*)d_in[5];
    const float* Wv       = (const float*)d_in[6];
    const float* Wo       = (const float*)d_in[7];
    const float* bo       = (const float*)d_in[8];
    const float* rel_table= (const float*)d_in[9];

    float* out = (float*)d_out;
    const size_t M1 = (size_t)1024 * 1024;
    unsigned short* xb   = (unsigned short*)d_ws;   //  2M
    unsigned short* memb = xb   + 2 * M1;           //  8M
    unsigned short* wt   = memb + 8 * M1;           //  4M
    unsigned short* qb   = wt   + 4 * M1;           //  2M  qh[b][h][q][dh]
    unsigned short* kb   = qb   + 2 * M1;           // 10M  kh[b][h][j][dh]
    unsigned short* vb   = kb   + 10 * M1;          // 10M  vt[b][h][dh][j]
    unsigned short* aob  = vb   + 10 * M1;          //  2M
    float* mbp = (float*)(aob + 2 * M1);            // 10240 floats

    prep_kernel<<<9256, 256, 0, stream>>>(
        x, mem, mask, Wq, Wk, Wv, Wo, xb, memb, wt, mbp);
    mgemm01_kernel<<<1408, 256, 0, stream>>>(
        xb, memb, wt, qb, kb, vb, rel_table, rel_idxs);
    attn6_kernel<<<dim3(16, 16, 2), 256, 0, stream>>>(qb, kb, vb, mbp, aob);
    // last dispatch: out-projection (z=0) + new_mem copy (z=1)
    mgemm2_kernel<<<dim3(8, 32, 2), 256, 0, stream>>>(
        aob, wt + 3 * M1, out, bo, x, out + (size_t)2048 * 1024);
}